// Round 9
// baseline (42.113 us; speedup 1.0000x reference)
//
#include <hip/hip_runtime.h>

#define N_TOK 4096
#define DMODEL 1024
#define NEXP 8
#define BT 512          // build-kernel threads
#define TPB 8           // tokens per build thread (512*8 = 4096)
#define RPB 16          // rows per block in gather/pad

typedef float vfloat4 __attribute__((ext_vector_type(4)));

// One block per expert. Stable-compacts selected token indices into
// perm[e][0..cnt) via block-wide LDS scan; writes f32 tags (token index,
// zero-padded), f32 counts to d_out, and i32 counts to ws for the
// gather/pad kernels. Every ws word rewritten each launch.
__global__ __launch_bounds__(BT) void build(
        const int* __restrict__ hot_mask,
        int* __restrict__ perm,          // ws: [E, N_TOK], token or -1
        int* __restrict__ cnt_i32,       // ws: [E]
        float* __restrict__ out_tags,    // [E, N_TOK] f32
        float* __restrict__ out_cnts) {  // [E] f32
    const int e = blockIdx.x;
    const int t = threadIdx.x;
    const int base = t * TPB;

    unsigned int bits = 0;
    int s = 0;
#pragma unroll
    for (int j = 0; j < TPB; ++j) {
        int m = (hot_mask[(size_t)(base + j) * NEXP + e] > 0) ? 1 : 0;
        bits |= (unsigned int)m << j;
        s += m;
    }

    __shared__ int sm[BT];
    sm[t] = s;
    __syncthreads();
    for (int off = 1; off < BT; off <<= 1) {   // inclusive scan
        int v = (t >= off) ? sm[t - off] : 0;
        __syncthreads();
        sm[t] += v;
        __syncthreads();
    }
    const int cnt = sm[BT - 1];
    int run = (t == 0) ? 0 : sm[t - 1];

#pragma unroll
    for (int j = 0; j < TPB; ++j) {
        if ((bits >> j) & 1u) {
            const int slot = run++;
            perm[e * N_TOK + slot] = base + j;
            out_tags[e * N_TOK + slot] = (float)(base + j);  // tag[n] == n
        }
    }
    for (int slot = cnt + t; slot < N_TOK; slot += BT) {
        perm[e * N_TOK + slot] = -1;
        out_tags[e * N_TOK + slot] = 0.0f;
    }
    if (t == 0) {
        out_cnts[e] = (float)cnt;
        cnt_i32[e] = cnt;
    }
}

// Valid rows only (slot < cnt_e): gather x[n]*score, nt float4 stores.
// Blocks entirely in the pad region exit after one scalar load.
__global__ __launch_bounds__(1024) void gather_valid(
        const float* __restrict__ x,
        const float* __restrict__ score,
        const int* __restrict__ perm,
        const int* __restrict__ cnt_i32,
        float* __restrict__ out_data)
{
    const int row0  = blockIdx.x * RPB;
    const int e     = row0 >> 12;
    const int slot0 = row0 & (N_TOK - 1);
    const int cnt   = cnt_i32[e];
    if (slot0 >= cnt) return;              // fully pad -> nothing to do here

    const int tid = threadIdx.x;
    __shared__ int   s_n[RPB];
    __shared__ float s_sc[RPB];
    if (tid < RPB) {
        const int n = perm[row0 + tid];
        s_n[tid] = n;
        s_sc[tid] = (n >= 0) ? score[(size_t)(n & (N_TOK - 1)) * NEXP + e] : 0.0f;
    }
    __syncthreads();

    const int t  = tid & 255;
    const int r0 = tid >> 8;
#pragma unroll
    for (int i = 0; i < 4; ++i) {
        const int r = r0 + 4 * i;
        const int n = s_n[r];
        if (n < 0) continue;               // pad row inside straddling block
        vfloat4 v = reinterpret_cast<const vfloat4*>(
                        x + (size_t)(n & (N_TOK - 1)) * DMODEL)[t];
        v *= s_sc[r];
        __builtin_nontemporal_store(
            v, reinterpret_cast<vfloat4*>(
                   out_data + (size_t)(row0 + r) * DMODEL) + t);
    }
}

// Pad rows only (slot >= cnt_e): pure zero write stream at fill-like rate.
// Blocks entirely in the valid region exit after one scalar load.
__global__ __launch_bounds__(1024) void pad_fill(
        const int* __restrict__ cnt_i32,
        float* __restrict__ out_data)
{
    const int row0  = blockIdx.x * RPB;
    const int e     = row0 >> 12;
    const int slot0 = row0 & (N_TOK - 1);
    const int cnt   = cnt_i32[e];
    if (slot0 + RPB <= cnt) return;        // fully valid -> gather's job

    const int tid = threadIdx.x;
    const int t  = tid & 255;
    const int r0 = tid >> 8;
    const vfloat4 z = (vfloat4)(0.f);
#pragma unroll
    for (int i = 0; i < 4; ++i) {
        const int r = r0 + 4 * i;
        if (slot0 + r < cnt) continue;     // valid row inside straddling block
        __builtin_nontemporal_store(
            z, reinterpret_cast<vfloat4*>(
                   out_data + (size_t)(row0 + r) * DMODEL) + t);
    }
}

extern "C" void kernel_launch(void* const* d_in, const int* in_sizes, int n_in,
                              void* d_out, int out_size, void* d_ws, size_t ws_size,
                              hipStream_t stream) {
    const float* x        = (const float*)d_in[0];   // [N, D] f32
    const float* score    = (const float*)d_in[1];   // [N, E] f32
    const int*   hot_mask = (const int*)d_in[2];     // [N, E] i32
    // d_in[3] = tag = arange(N); token index IS the tag.

    float* out      = (float*)d_out;                          // f32 outputs
    float* out_data = out;                                    // [E,N,D]
    float* out_tags = out + (size_t)NEXP * N_TOK * DMODEL;    // [E,N,1]
    float* out_cnts = out_tags + (size_t)NEXP * N_TOK;        // [E]

    int* perm    = (int*)d_ws;                                // [E, N_TOK]
    int* cnt_i32 = perm + NEXP * N_TOK;                       // [E]

    const int nblk = (NEXP * N_TOK) / RPB;
    build<<<NEXP, BT, 0, stream>>>(hot_mask, perm, cnt_i32, out_tags, out_cnts);
    gather_valid<<<nblk, 1024, 0, stream>>>(x, score, perm, cnt_i32, out_data);
    pad_fill<<<nblk, 1024, 0, stream>>>(cnt_i32, out_data);
}

// Round 10
// 36.768 us; speedup vs baseline: 1.1454x; 1.1454x over previous
//
#include <hip/hip_runtime.h>

#define N_TOK 4096
#define DMODEL 1024
#define NEXP 8
#define BT 512          // build-kernel threads
#define TPB 8           // tokens per build thread (512*8 = 4096)
#define PRPB 16         // pad rows per pad block

typedef float vfloat4 __attribute__((ext_vector_type(4)));

// One block per expert. Block-wide LDS scan of the mask column; emits the
// INVERSE slot map islot[n][e] (slot index, or -1 if token n not routed to
// expert e), f32 tags (token index, zero-padded), f32 + i32 counts. Every
// islot word is rewritten each launch.
__global__ __launch_bounds__(BT) void build(
        const int* __restrict__ hot_mask,
        int* __restrict__ islot,         // ws: [N_TOK][NEXP], slot or -1
        int* __restrict__ cnt_i32,       // ws: [E]
        float* __restrict__ out_tags,    // [E, N_TOK] f32
        float* __restrict__ out_cnts) {  // [E] f32
    const int e = blockIdx.x;
    const int t = threadIdx.x;
    const int base = t * TPB;

    unsigned int bits = 0;
    int s = 0;
#pragma unroll
    for (int j = 0; j < TPB; ++j) {
        int m = (hot_mask[(size_t)(base + j) * NEXP + e] > 0) ? 1 : 0;
        bits |= (unsigned int)m << j;
        s += m;
    }

    __shared__ int sm[BT];
    sm[t] = s;
    __syncthreads();
    for (int off = 1; off < BT; off <<= 1) {   // inclusive scan
        int v = (t >= off) ? sm[t - off] : 0;
        __syncthreads();
        sm[t] += v;
        __syncthreads();
    }
    const int cnt = sm[BT - 1];
    int run = (t == 0) ? 0 : sm[t - 1];        // exclusive prefix

#pragma unroll
    for (int j = 0; j < TPB; ++j) {
        const int tok = base + j;
        int sl = -1;
        if ((bits >> j) & 1u) {
            sl = run++;
            out_tags[e * N_TOK + sl] = (float)tok;   // tag[n] == n
        }
        islot[tok * NEXP + e] = sl;
    }
    for (int slot = cnt + t; slot < N_TOK; slot += BT)
        out_tags[e * N_TOK + slot] = 0.0f;
    if (t == 0) {
        out_cnts[e] = (float)cnt;
        cnt_i32[e] = cnt;
    }
}

// Token-centric scatter + pad fill in ONE dispatch.
// Blocks [0, N_TOK): block n reads x[n] ONCE (float4/thread), then writes a
// scaled copy into each expert that selected n (islot >= 0). Cuts logical x
// reads 4x vs row-gather (67 -> 17 MB).
// Blocks [N_TOK, N_TOK + 2048): pure zero-fill of pad rows (slot >= cnt_e).
// Together they write every data element exactly once per launch.
__global__ __launch_bounds__(256) void scatter_and_pad(
        const float* __restrict__ x,
        const float* __restrict__ score,
        const int* __restrict__ islot,
        const int* __restrict__ cnt_i32,
        float* __restrict__ out_data)
{
    const int b = blockIdx.x;
    const int t = threadIdx.x;                 // 256 threads x float4 = DMODEL

    if (b < N_TOK) {
        const int n = b;
        const vfloat4 v = reinterpret_cast<const vfloat4*>(
                              x + (size_t)n * DMODEL)[t];
#pragma unroll
        for (int e = 0; e < NEXP; ++e) {
            const int sl = islot[n * NEXP + e];      // uniform -> scalar load
            if (sl >= 0) {
                vfloat4 w = v * score[n * NEXP + e];
                __builtin_nontemporal_store(
                    w, reinterpret_cast<vfloat4*>(
                           out_data + ((size_t)e * N_TOK + sl) * DMODEL) + t);
            }
        }
    } else {
        const int row0  = (b - N_TOK) * PRPB;        // global row = e*N_TOK+slot
        const int e     = row0 >> 12;
        const int slot0 = row0 & (N_TOK - 1);
        const int cnt   = cnt_i32[e];
        if (slot0 + PRPB <= cnt) return;             // fully valid region
        const vfloat4 z = (vfloat4)(0.f);
        for (int r = 0; r < PRPB; ++r) {
            if (slot0 + r < cnt) continue;
            __builtin_nontemporal_store(
                z, reinterpret_cast<vfloat4*>(
                       out_data + (size_t)(row0 + r) * DMODEL) + t);
        }
    }
}

extern "C" void kernel_launch(void* const* d_in, const int* in_sizes, int n_in,
                              void* d_out, int out_size, void* d_ws, size_t ws_size,
                              hipStream_t stream) {
    const float* x        = (const float*)d_in[0];   // [N, D] f32
    const float* score    = (const float*)d_in[1];   // [N, E] f32
    const int*   hot_mask = (const int*)d_in[2];     // [N, E] i32
    // d_in[3] = tag = arange(N); token index IS the tag.

    float* out      = (float*)d_out;                          // f32 outputs
    float* out_data = out;                                    // [E,N,D]
    float* out_tags = out + (size_t)NEXP * N_TOK * DMODEL;    // [E,N,1]
    float* out_cnts = out_tags + (size_t)NEXP * N_TOK;        // [E]

    int* islot   = (int*)d_ws;                                // [N_TOK][NEXP]
    int* cnt_i32 = islot + N_TOK * NEXP;                      // [E]

    const int npad = (NEXP * N_TOK) / PRPB;                   // 2048
    build<<<NEXP, BT, 0, stream>>>(hot_mask, islot, cnt_i32, out_tags, out_cnts);
    scatter_and_pad<<<N_TOK + npad, 256, 0, stream>>>(
        x, score, islot, cnt_i32, out_data);
}

// Round 11
// 34.745 us; speedup vs baseline: 1.2121x; 1.0582x over previous
//
#include <hip/hip_runtime.h>

#define N_TOK 4096
#define DMODEL 1024
#define NEXP 8
#define BT 512          // build-kernel threads
#define TPB 8           // tokens per build thread (512*8 = 4096)
#define PRPB 16         // pad rows per pad block

typedef float vfloat4 __attribute__((ext_vector_type(4)));

// One block per expert. Block-wide LDS scan of the mask column; emits the
// INVERSE slot map islot[n][e] (slot index, or -1 if token n not routed to
// expert e), f32 tags (token index, zero-padded), f32 + i32 counts. Every
// islot word is rewritten each launch.
__global__ __launch_bounds__(BT) void build(
        const int* __restrict__ hot_mask,
        int* __restrict__ islot,         // ws: [N_TOK][NEXP], slot or -1
        int* __restrict__ cnt_i32,       // ws: [E]
        float* __restrict__ out_tags,    // [E, N_TOK] f32
        float* __restrict__ out_cnts) {  // [E] f32
    const int e = blockIdx.x;
    const int t = threadIdx.x;
    const int base = t * TPB;

    unsigned int bits = 0;
    int s = 0;
#pragma unroll
    for (int j = 0; j < TPB; ++j) {
        int m = (hot_mask[(size_t)(base + j) * NEXP + e] > 0) ? 1 : 0;
        bits |= (unsigned int)m << j;
        s += m;
    }

    __shared__ int sm[BT];
    sm[t] = s;
    __syncthreads();
    for (int off = 1; off < BT; off <<= 1) {   // inclusive scan
        int v = (t >= off) ? sm[t - off] : 0;
        __syncthreads();
        sm[t] += v;
        __syncthreads();
    }
    const int cnt = sm[BT - 1];
    int run = (t == 0) ? 0 : sm[t - 1];        // exclusive prefix

#pragma unroll
    for (int j = 0; j < TPB; ++j) {
        const int tok = base + j;
        int sl = -1;
        if ((bits >> j) & 1u) {
            sl = run++;
            out_tags[e * N_TOK + sl] = (float)tok;   // tag[n] == n
        }
        islot[tok * NEXP + e] = sl;
    }
    for (int slot = cnt + t; slot < N_TOK; slot += BT)
        out_tags[e * N_TOK + slot] = 0.0f;
    if (t == 0) {
        out_cnts[e] = (float)cnt;
        cnt_i32[e] = cnt;
    }
}

// Token-centric scatter + pad fill in ONE dispatch. Identical to round 10
// EXCEPT: regular (cached) stores instead of __builtin_nontemporal_store.
// A/B test: is the nt path capping the write stream at ~4.6 TB/s?
__global__ __launch_bounds__(256) void scatter_and_pad(
        const float* __restrict__ x,
        const float* __restrict__ score,
        const int* __restrict__ islot,
        const int* __restrict__ cnt_i32,
        float* __restrict__ out_data)
{
    const int b = blockIdx.x;
    const int t = threadIdx.x;                 // 256 threads x float4 = DMODEL

    if (b < N_TOK) {
        const int n = b;
        const vfloat4 v = reinterpret_cast<const vfloat4*>(
                              x + (size_t)n * DMODEL)[t];
#pragma unroll
        for (int e = 0; e < NEXP; ++e) {
            const int sl = islot[n * NEXP + e];      // uniform -> scalar load
            if (sl >= 0) {
                vfloat4 w = v * score[n * NEXP + e];
                reinterpret_cast<vfloat4*>(
                    out_data + ((size_t)e * N_TOK + sl) * DMODEL)[t] = w;
            }
        }
    } else {
        const int row0  = (b - N_TOK) * PRPB;        // global row = e*N_TOK+slot
        const int e     = row0 >> 12;
        const int slot0 = row0 & (N_TOK - 1);
        const int cnt   = cnt_i32[e];
        if (slot0 + PRPB <= cnt) return;             // fully valid region
        const vfloat4 z = (vfloat4)(0.f);
        for (int r = 0; r < PRPB; ++r) {
            if (slot0 + r < cnt) continue;
            reinterpret_cast<vfloat4*>(
                out_data + (size_t)(row0 + r) * DMODEL)[t] = z;
        }
    }
}

extern "C" void kernel_launch(void* const* d_in, const int* in_sizes, int n_in,
                              void* d_out, int out_size, void* d_ws, size_t ws_size,
                              hipStream_t stream) {
    const float* x        = (const float*)d_in[0];   // [N, D] f32
    const float* score    = (const float*)d_in[1];   // [N, E] f32
    const int*   hot_mask = (const int*)d_in[2];     // [N, E] i32
    // d_in[3] = tag = arange(N); token index IS the tag.

    float* out      = (float*)d_out;                          // f32 outputs
    float* out_data = out;                                    // [E,N,D]
    float* out_tags = out + (size_t)NEXP * N_TOK * DMODEL;    // [E,N,1]
    float* out_cnts = out_tags + (size_t)NEXP * N_TOK;        // [E]

    int* islot   = (int*)d_ws;                                // [N_TOK][NEXP]
    int* cnt_i32 = islot + N_TOK * NEXP;                      // [E]

    const int npad = (NEXP * N_TOK) / PRPB;                   // 2048
    build<<<NEXP, BT, 0, stream>>>(hot_mask, islot, cnt_i32, out_tags, out_cnts);
    scatter_and_pad<<<N_TOK + npad, 256, 0, stream>>>(
        x, score, islot, cnt_i32, out_data);
}

// Round 12
// 34.364 us; speedup vs baseline: 1.2255x; 1.0111x over previous
//
#include <hip/hip_runtime.h>

#define N_TOK 4096
#define DMODEL 1024
#define NEXP 8
#define BT 1024         // build-kernel threads
#define TPB 4           // tokens per build thread (1024*4 = 4096)
#define PRPB 16         // pad rows per scatter block (2048 blocks * 16 = 32768)

typedef float vfloat4 __attribute__((ext_vector_type(4)));

// One block per expert. Block-wide LDS scan of the mask column; emits the
// INVERSE slot map islot[n][e] (slot index, or -1 if token n not routed to
// expert e), f32 tags (token index, zero-padded), f32 + i32 counts. Every
// ws word rewritten each launch.
__global__ __launch_bounds__(BT) void build(
        const int* __restrict__ hot_mask,
        int* __restrict__ islot,         // ws: [N_TOK][NEXP], slot or -1
        int* __restrict__ cnt_i32,       // ws: [E]
        float* __restrict__ out_tags,    // [E, N_TOK] f32
        float* __restrict__ out_cnts) {  // [E] f32
    const int e = blockIdx.x;
    const int t = threadIdx.x;
    const int base = t * TPB;

    unsigned int bits = 0;
    int s = 0;
#pragma unroll
    for (int j = 0; j < TPB; ++j) {
        int m = (hot_mask[(size_t)(base + j) * NEXP + e] > 0) ? 1 : 0;
        bits |= (unsigned int)m << j;
        s += m;
    }

    __shared__ int sm[BT];
    sm[t] = s;
    __syncthreads();
    for (int off = 1; off < BT; off <<= 1) {   // inclusive scan (10 rounds)
        int v = (t >= off) ? sm[t - off] : 0;
        __syncthreads();
        sm[t] += v;
        __syncthreads();
    }
    const int cnt = sm[BT - 1];
    int run = (t == 0) ? 0 : sm[t - 1];        // exclusive prefix

#pragma unroll
    for (int j = 0; j < TPB; ++j) {
        const int tok = base + j;
        int sl = -1;
        if ((bits >> j) & 1u) {
            sl = run++;
            out_tags[e * N_TOK + sl] = (float)tok;   // tag[n] == n
        }
        islot[tok * NEXP + e] = sl;
    }
    for (int slot = cnt + t; slot < N_TOK; slot += BT)
        out_tags[e * N_TOK + slot] = 0.0f;
    if (t == 0) {
        out_cnts[e] = (float)cnt;
        cnt_i32[e] = cnt;
    }
}

// Persistent-style merged scatter+pad: 2048 blocks, each owns 2 tokens and
// exactly 1 pad chunk (16 rows) -- perfect partition, no early-exit blocks.
// Two independent x-row loads + all islot/score scalar loads issue up
// front (2x MLP vs round 11); all stores independent. Regular cached
// stores (round-11 A/B: nt-stores cost ~2 us). Every data element written
// exactly once per launch.
__global__ __launch_bounds__(256) void scatter_pad(
        const float* __restrict__ x,
        const float* __restrict__ score,
        const int* __restrict__ islot,
        const int* __restrict__ cnt_i32,
        float* __restrict__ out_data)
{
    const int b = blockIdx.x;              // 0..2047
    const int t = threadIdx.x;             // 256 threads x float4 = DMODEL
    const int n0 = 2 * b, n1 = 2 * b + 1;

    // issue both x-row loads early (independent)
    const vfloat4 v0 = reinterpret_cast<const vfloat4*>(x + (size_t)n0 * DMODEL)[t];
    const vfloat4 v1 = reinterpret_cast<const vfloat4*>(x + (size_t)n1 * DMODEL)[t];

#pragma unroll
    for (int e = 0; e < NEXP; ++e) {
        const int sl = islot[n0 * NEXP + e];       // uniform -> scalar load
        if (sl >= 0) {
            vfloat4 w = v0 * score[n0 * NEXP + e];
            reinterpret_cast<vfloat4*>(
                out_data + ((size_t)e * N_TOK + sl) * DMODEL)[t] = w;
        }
    }
#pragma unroll
    for (int e = 0; e < NEXP; ++e) {
        const int sl = islot[n1 * NEXP + e];
        if (sl >= 0) {
            vfloat4 w = v1 * score[n1 * NEXP + e];
            reinterpret_cast<vfloat4*>(
                out_data + ((size_t)e * N_TOK + sl) * DMODEL)[t] = w;
        }
    }

    // pad chunk b: zero rows with slot >= cnt_e in [16b, 16b+16)
    const int row0  = b * PRPB;                    // global row = e*N_TOK+slot
    const int e     = row0 >> 12;
    const int slot0 = row0 & (N_TOK - 1);
    const int cnt   = cnt_i32[e];
    if (slot0 + PRPB > cnt) {
        const vfloat4 z = (vfloat4)(0.f);
        for (int r = 0; r < PRPB; ++r) {
            if (slot0 + r < cnt) continue;
            reinterpret_cast<vfloat4*>(
                out_data + (size_t)(row0 + r) * DMODEL)[t] = z;
        }
    }
}

extern "C" void kernel_launch(void* const* d_in, const int* in_sizes, int n_in,
                              void* d_out, int out_size, void* d_ws, size_t ws_size,
                              hipStream_t stream) {
    const float* x        = (const float*)d_in[0];   // [N, D] f32
    const float* score    = (const float*)d_in[1];   // [N, E] f32
    const int*   hot_mask = (const int*)d_in[2];     // [N, E] i32
    // d_in[3] = tag = arange(N); token index IS the tag.

    float* out      = (float*)d_out;                          // f32 outputs
    float* out_data = out;                                    // [E,N,D]
    float* out_tags = out + (size_t)NEXP * N_TOK * DMODEL;    // [E,N,1]
    float* out_cnts = out_tags + (size_t)NEXP * N_TOK;        // [E]

    int* islot   = (int*)d_ws;                                // [N_TOK][NEXP]
    int* cnt_i32 = islot + N_TOK * NEXP;                      // [E]

    build<<<NEXP, BT, 0, stream>>>(hot_mask, islot, cnt_i32, out_tags, out_cnts);
    scatter_pad<<<N_TOK / 2, 256, 0, stream>>>(
        x, score, islot, cnt_i32, out_data);
}

// Round 13
// 32.838 us; speedup vs baseline: 1.2824x; 1.0465x over previous
//
#include <hip/hip_runtime.h>

#define N_TOK 4096
#define DMODEL 1024
#define NEXP 8
#define PRPB 16         // pad rows per scatter block (2048 blocks * 16 = 32768)

typedef float vfloat4 __attribute__((ext_vector_type(4)));

// One block (1024 thr = 16 waves) per expert. Ballot-based stable compaction
// (proven in round 7): 4 ballot rounds over 1024 tokens each -> 64 wave sums
// -> single-wave shfl inclusive scan -> per-token slot. Only 2 __syncthreads
// (vs 20 for the LDS Hillis-Steele scan). Emits inverse map islot[n][e]
// (slot or -1), f32 tags (zero-padded), f32+i32 counts. Every ws word
// rewritten each launch.
__global__ __launch_bounds__(1024) void build(
        const int* __restrict__ hot_mask,
        int* __restrict__ islot,         // ws: [N_TOK][NEXP], slot or -1
        int* __restrict__ cnt_i32,       // ws: [E]
        float* __restrict__ out_tags,    // [E, N_TOK] f32
        float* __restrict__ out_cnts) {  // [E] f32
    const int e    = blockIdx.x;
    const int tid  = threadIdx.x;        // 0..1023
    const int wave = tid >> 6;
    const int lane = tid & 63;

    __shared__ int wsum[64];             // (round j, wave w) counts -> scan

    // Phase A: ballots; token order == (j, wave, lane)
    unsigned long long bal[4];
#pragma unroll
    for (int j = 0; j < 4; ++j) {
        const int tok = j * 1024 + tid;
        const int m = (hot_mask[(size_t)tok * NEXP + e] > 0) ? 1 : 0;
        bal[j] = __ballot(m);
        if (lane == 0) wsum[j * 16 + wave] = (int)__popcll(bal[j]);
    }
    __syncthreads();

    // Phase B: inclusive scan of 64 wave-sums by wave 0 (shfl, no barriers)
    if (wave == 0) {
        int v = wsum[lane];
#pragma unroll
        for (int off = 1; off < 64; off <<= 1) {
            int u = __shfl_up(v, off);
            if (lane >= off) v += u;
        }
        wsum[lane] = v;
    }
    __syncthreads();
    const int cnt = wsum[63];

    // Phase C: per-token slot; write islot for ALL tokens, tags for selected
#pragma unroll
    for (int j = 0; j < 4; ++j) {
        const int tok = j * 1024 + tid;
        const int idx = j * 16 + wave;
        int sl = -1;
        if ((bal[j] >> lane) & 1ull) {
            sl = (idx ? wsum[idx - 1] : 0)
               + (int)__popcll(bal[j] & ((1ull << lane) - 1ull));
            out_tags[e * N_TOK + sl] = (float)tok;   // tag[n] == n
        }
        islot[tok * NEXP + e] = sl;
    }
    for (int slot = cnt + tid; slot < N_TOK; slot += 1024)
        out_tags[e * N_TOK + slot] = 0.0f;
    if (tid == 0) {
        out_cnts[e] = (float)cnt;
        cnt_i32[e] = cnt;
    }
}

// Merged scatter+pad (unchanged from round 12, current best): 2048 blocks,
// each owns 2 tokens and exactly 1 pad chunk (16 rows). Regular cached
// stores (round-11 A/B: nt-stores cost ~2 us). Every data element written
// exactly once per launch.
__global__ __launch_bounds__(256) void scatter_pad(
        const float* __restrict__ x,
        const float* __restrict__ score,
        const int* __restrict__ islot,
        const int* __restrict__ cnt_i32,
        float* __restrict__ out_data)
{
    const int b = blockIdx.x;              // 0..2047
    const int t = threadIdx.x;             // 256 threads x float4 = DMODEL
    const int n0 = 2 * b, n1 = 2 * b + 1;

    const vfloat4 v0 = reinterpret_cast<const vfloat4*>(x + (size_t)n0 * DMODEL)[t];
    const vfloat4 v1 = reinterpret_cast<const vfloat4*>(x + (size_t)n1 * DMODEL)[t];

#pragma unroll
    for (int e = 0; e < NEXP; ++e) {
        const int sl = islot[n0 * NEXP + e];
        if (sl >= 0) {
            vfloat4 w = v0 * score[n0 * NEXP + e];
            reinterpret_cast<vfloat4*>(
                out_data + ((size_t)e * N_TOK + sl) * DMODEL)[t] = w;
        }
    }
#pragma unroll
    for (int e = 0; e < NEXP; ++e) {
        const int sl = islot[n1 * NEXP + e];
        if (sl >= 0) {
            vfloat4 w = v1 * score[n1 * NEXP + e];
            reinterpret_cast<vfloat4*>(
                out_data + ((size_t)e * N_TOK + sl) * DMODEL)[t] = w;
        }
    }

    // pad chunk b: zero rows with slot >= cnt_e in [16b, 16b+16)
    const int row0  = b * PRPB;
    const int e     = row0 >> 12;
    const int slot0 = row0 & (N_TOK - 1);
    const int cnt   = cnt_i32[e];
    if (slot0 + PRPB > cnt) {
        const vfloat4 z = (vfloat4)(0.f);
        for (int r = 0; r < PRPB; ++r) {
            if (slot0 + r < cnt) continue;
            reinterpret_cast<vfloat4*>(
                out_data + (size_t)(row0 + r) * DMODEL)[t] = z;
        }
    }
}

extern "C" void kernel_launch(void* const* d_in, const int* in_sizes, int n_in,
                              void* d_out, int out_size, void* d_ws, size_t ws_size,
                              hipStream_t stream) {
    const float* x        = (const float*)d_in[0];   // [N, D] f32
    const float* score    = (const float*)d_in[1];   // [N, E] f32
    const int*   hot_mask = (const int*)d_in[2];     // [N, E] i32
    // d_in[3] = tag = arange(N); token index IS the tag.

    float* out      = (float*)d_out;                          // f32 outputs
    float* out_data = out;                                    // [E,N,D]
    float* out_tags = out + (size_t)NEXP * N_TOK * DMODEL;    // [E,N,1]
    float* out_cnts = out_tags + (size_t)NEXP * N_TOK;        // [E]

    int* islot   = (int*)d_ws;                                // [N_TOK][NEXP]
    int* cnt_i32 = islot + N_TOK * NEXP;                      // [E]

    build<<<NEXP, 1024, 0, stream>>>(hot_mask, islot, cnt_i32, out_tags, out_cnts);
    scatter_pad<<<N_TOK / 2, 256, 0, stream>>>(
        x, score, islot, cnt_i32, out_data);
}

// Round 14
// 32.666 us; speedup vs baseline: 1.2892x; 1.0053x over previous
//
#include <hip/hip_runtime.h>

#define N_TOK 4096
#define DMODEL 1024
#define NEXP 8
#define NCHUNK 64       // 64 chunks x 64 tokens = 4096

typedef float vfloat4 __attribute__((ext_vector_type(4)));

// Single fused dispatch. Block b = (expert e = b>>6, chunk c = b&63).
// Phase A: ballot-scan the whole mask column of e (16 ballots, L2-hot).
// Phase B: wave-0 shfl inclusive scan of the 64 chunk sums -> prefix, cnt.
// Phase C: wave 0 lists this chunk's selected tokens (slot, score, tags).
// Phase D: all 256 threads stream the valid rows: out[e][slot] = x[tok]*sc.
// Phase E: block zero-fills its 1/64 share of the expert's pad rows + tags.
// Valid slots are disjoint across blocks (disjoint chunk prefixes); pad
// shares partition [cnt, N) exactly. Every output element written exactly
// once per launch; no workspace; deterministic.
__global__ __launch_bounds__(256) void dispatch_one(
        const float* __restrict__ x,        // [N, D]
        const float* __restrict__ score,    // [N, E]
        const int*   __restrict__ hot_mask, // [N, E]
        float* __restrict__ out_data,       // [E, N, D]
        float* __restrict__ out_tags,       // [E, N]
        float* __restrict__ out_cnts)       // [E]
{
    const int b    = blockIdx.x;            // 0..511
    const int e    = b >> 6;
    const int c    = b & (NCHUNK - 1);
    const int tid  = threadIdx.x;            // 0..255 (4 waves)
    const int wave = tid >> 6;
    const int lane = tid & 63;

    __shared__ int   wsum[NCHUNK];           // per-chunk popcounts
    __shared__ int   scan[NCHUNK];           // inclusive scan of wsum
    __shared__ int   s_tok[64];              // this chunk's selected tokens
    __shared__ int   s_slot[64];
    __shared__ float s_sc[64];
    __shared__ int   s_nsel;

    // Phase A: 16 ballot rounds; wave w in round j covers chunk j*4+w
#pragma unroll
    for (int j = 0; j < 16; ++j) {
        const int tok = j * 256 + tid;
        const int m = (hot_mask[(size_t)tok * NEXP + e] > 0) ? 1 : 0;
        const unsigned long long bal = __ballot(m);
        if (lane == 0) wsum[j * 4 + wave] = (int)__popcll(bal);
    }
    __syncthreads();

    // Phase B: inclusive scan of 64 chunk sums (wave 0, shfl)
    if (wave == 0) {
        int v = wsum[lane];
#pragma unroll
        for (int off = 1; off < 64; off <<= 1) {
            int u = __shfl_up(v, off);
            if (lane >= off) v += u;
        }
        scan[lane] = v;
    }
    __syncthreads();
    const int cnt  = scan[NCHUNK - 1];
    const int pref = c ? scan[c - 1] : 0;

    // Phase C: wave 0 builds the work list for chunk c (+ tags for selected)
    if (wave == 0) {
        const int tok = c * 64 + lane;
        const int m = (hot_mask[(size_t)tok * NEXP + e] > 0) ? 1 : 0;
        const unsigned long long bal = __ballot(m);
        if (lane == 0) s_nsel = (int)__popcll(bal);
        if (m) {
            const int idx = (int)__popcll(bal & ((1ull << lane) - 1ull));
            const int sl = pref + idx;
            s_tok[idx]  = tok;
            s_slot[idx] = sl;
            s_sc[idx]   = score[(size_t)tok * NEXP + e];
            out_tags[e * N_TOK + sl] = (float)tok;   // tag[n] == n
        }
    }
    __syncthreads();
    const int nsel = s_nsel;

    // Phase D: stream valid rows (x read once per selected (tok,e))
    for (int i = 0; i < nsel; ++i) {
        const int tok = s_tok[i];
        vfloat4 v = reinterpret_cast<const vfloat4*>(x + (size_t)tok * DMODEL)[tid];
        v *= s_sc[i];
        reinterpret_cast<vfloat4*>(
            out_data + ((size_t)e * N_TOK + s_slot[i]) * DMODEL)[tid] = v;
    }

    // Phase E: this block's share of the pad region [cnt, N)
    const int sh = (N_TOK - cnt + NCHUNK - 1) >> 6;   // rows per block share
    const int lo = cnt + c * sh;
    const int hi = min(lo + sh, N_TOK);
    const vfloat4 z = (vfloat4)(0.f);
    for (int r = lo; r < hi; ++r)
        reinterpret_cast<vfloat4*>(
            out_data + ((size_t)e * N_TOK + r) * DMODEL)[tid] = z;
    if (lo + tid < hi) out_tags[e * N_TOK + lo + tid] = 0.0f;  // sh <= 64 < 256

    if (c == 0 && tid == 0) out_cnts[e] = (float)cnt;
}

extern "C" void kernel_launch(void* const* d_in, const int* in_sizes, int n_in,
                              void* d_out, int out_size, void* d_ws, size_t ws_size,
                              hipStream_t stream) {
    const float* x        = (const float*)d_in[0];   // [N, D] f32
    const float* score    = (const float*)d_in[1];   // [N, E] f32
    const int*   hot_mask = (const int*)d_in[2];     // [N, E] i32
    // d_in[3] = tag = arange(N); token index IS the tag.

    float* out      = (float*)d_out;                          // f32 outputs
    float* out_data = out;                                    // [E,N,D]
    float* out_tags = out + (size_t)NEXP * N_TOK * DMODEL;    // [E,N,1]
    float* out_cnts = out_tags + (size_t)NEXP * N_TOK;        // [E]

    dispatch_one<<<NEXP * NCHUNK, 256, 0, stream>>>(
        x, score, hot_mask, out_data, out_tags, out_cnts);
}